// Round 8
// baseline (4803.735 us; speedup 1.0000x reference)
//
#include <hip/hip_runtime.h>
#include <math.h>

#define HH 512
#define BB 64
#define SS 48
#define EE 512
#define G4 2048
#define EPSF 1e-5f
#define AGENT __HIP_MEMORY_SCOPE_AGENT

__device__ __forceinline__ float aload(const float* p) {
  return __hip_atomic_load(p, __ATOMIC_RELAXED, AGENT);
}
__device__ __forceinline__ void astore(float* p, float v) {
  __hip_atomic_store(p, v, __ATOMIC_RELAXED, AGENT);
}

// counting barrier (preamble only)
__device__ __forceinline__ void gsync(int* c, int target) {
  __builtin_amdgcn_s_waitcnt(0);
  __syncthreads();
  if (threadIdx.x == 0) {
    __hip_atomic_fetch_add(c, 1, __ATOMIC_RELEASE, AGENT);
    int spins = 0;
    while (__hip_atomic_load(c, __ATOMIC_RELAXED, AGENT) < target) {
      __builtin_amdgcn_s_sleep(2);
      if (++spins > (1 << 21)) break;
    }
    (void)__hip_atomic_load(c, __ATOMIC_ACQUIRE, AGENT);
  }
  __syncthreads();
}

// ======== phase A: layer-0 input projection, full S, both dirs ========
__global__ __launch_bounds__(256)
void gemm_ih0(const float* __restrict__ x, const float* __restrict__ w_ih0,
              float* __restrict__ G0) {
  __shared__ float As[16][65];
  __shared__ float Bs[16][65];
  const int m0 = blockIdx.y * 64;
  const int d  = m0 / (BB * SS);
  const float* Wm = w_ih0 + (size_t)d * G4 * EE;
  const int bn = blockIdx.x * 64;
  const int tid = threadIdx.x;
  const int lrow = tid >> 2;
  const int lkk  = (tid & 3) << 2;
  const int tx = tid & 15;
  const int ty = tid >> 4;
  int m  = m0 + lrow;
  int r  = m - d * (BB * SS);
  int b  = r / SS;
  int tl = r - b * SS;
  int s  = d ? (SS - 1 - tl) : tl;
  const float* arow = x + ((size_t)b * SS + s) * EE;

  float acc[4][4] = {};
  for (int k0 = 0; k0 < EE; k0 += 16) {
    float4 av = *(const float4*)(arow + k0 + lkk);
    float4 bv = *(const float4*)(Wm + (size_t)(bn + lrow) * EE + k0 + lkk);
    As[lkk+0][lrow] = av.x; As[lkk+1][lrow] = av.y; As[lkk+2][lrow] = av.z; As[lkk+3][lrow] = av.w;
    Bs[lkk+0][lrow] = bv.x; Bs[lkk+1][lrow] = bv.y; Bs[lkk+2][lrow] = bv.z; Bs[lkk+3][lrow] = bv.w;
    __syncthreads();
    #pragma unroll
    for (int k = 0; k < 16; ++k) {
      float a[4], bbv[4];
      #pragma unroll
      for (int i = 0; i < 4; ++i) a[i] = As[k][ty*4+i];
      #pragma unroll
      for (int j = 0; j < 4; ++j) bbv[j] = Bs[k][tx*4+j];
      #pragma unroll
      for (int i = 0; i < 4; ++i)
        #pragma unroll
        for (int j = 0; j < 4; ++j) acc[i][j] += a[i]*bbv[j];
    }
    __syncthreads();
  }
  for (int i = 0; i < 4; ++i)
    for (int j = 0; j < 4; ++j)
      G0[(size_t)(m0 + ty*4 + i) * G4 + bn + tx*4 + j] = acc[i][j];
}

// ======== in-place LayerNorm on rows of 2048 ========
__global__ __launch_bounds__(256)
void ln_rows(float* __restrict__ X, const float* __restrict__ gamma,
             const float* __restrict__ beta, int rows_per_d) {
  __shared__ float red[8];
  const int row = blockIdx.x;
  const int d = row / rows_per_d;
  float* xr = X + (size_t)row * G4;
  const float* gg = gamma + (size_t)d * G4;
  const float* bb = beta  + (size_t)d * G4;
  float s = 0.f, q = 0.f;
  float v[8];
  #pragma unroll
  for (int it = 0; it < 8; ++it) {
    float xv = xr[threadIdx.x + it*256];
    v[it] = xv; s += xv; q += xv*xv;
  }
  #pragma unroll
  for (int off = 32; off > 0; off >>= 1) { s += __shfl_down(s, off); q += __shfl_down(q, off); }
  int lane = threadIdx.x & 63, wid = threadIdx.x >> 6;
  if (lane == 0) { red[wid] = s; red[4+wid] = q; }
  __syncthreads();
  float ts = red[0]+red[1]+red[2]+red[3];
  float tq = red[4]+red[5]+red[6]+red[7];
  float mu = ts * (1.f/G4);
  float rstd = rsqrtf(tq*(1.f/G4) - mu*mu + EPSF);
  #pragma unroll
  for (int it = 0; it < 8; ++it) {
    int jc = threadIdx.x + it*256;
    xr[jc] = (v[it]-mu)*rstd*gg[jc] + bb[jc];
  }
}

// ======== persistent scan: ONE barrier/step, replicated cell update ========
// group g = bb&7 = (d, bq); jb = bb>>3 in [0,32). Block owns 64 n-cols for
// the R-GEMV (weights in VGPRs, wave = k-slice of 32). After publishing its
// R slice + flag, EVERY block reads the full R tile for its 16 batches and
// redundantly computes the cell update (wave = one batch; stats are pure
// wave-shuffle reductions). h never leaves the block (straight into LDS).
// Rbuf is double-buffered by t-parity; flags are monotone step counters
// (one slot per block, no RMW contention).
__global__ __launch_bounds__(1024)
void persist5(const float* __restrict__ whh, const float* __restrict__ Gbuf,
              long g_row_stride, long g_t_stride,
              const float* __restrict__ lnhg, const float* __restrict__ lnhb,
              const float* __restrict__ lnog, const float* __restrict__ lnob,
              float* Rbuf, int* flags, float* fout, int nsteps,
              int mode1, const float* __restrict__ w_ih1,
              const float* __restrict__ xcb, float* g1pre,
              const float* __restrict__ ln_g1, const float* __restrict__ ln_b1,
              int* cnt_pre) {
  __shared__ float hlds[16][512];     // 32 KB
  __shared__ float part[16][16][64];  // 64 KB  -> 96 KB total => 1 block/CU
  __shared__ float sred[32];

  const int bb = blockIdx.x;
  const int tid = threadIdx.x;
  const int l = tid & 63;             // lane
  const int w = tid >> 6;             // wave (k-slice in GEMV, batch in update)

  // ---- mode1 preamble: layer-1 projection + LN(g1pre) ----
  if (mode1) {
    const int dp = bb & 1, nbp = bb >> 1;      // nbp in [0,128)
    const int pb = tid >> 4, ns = tid & 15;    // pb in [0,64)
    const int col = nbp*16 + ns;
    const float* xrow = xcb + (size_t)pb * 1024;
    const float* wv_ = w_ih1 + ((size_t)dp*G4 + col) * 1024;
    float a = 0.f;
    for (int k = 0; k < 1024; k += 4) {
      float4 xv = *(const float4*)(xrow + k);
      float4 wv4 = *(const float4*)(wv_ + k);
      a += xv.x*wv4.x + xv.y*wv4.y + xv.z*wv4.z + xv.w*wv4.w;
    }
    astore(g1pre + ((size_t)dp*BB + pb) * G4 + col, a);
    gsync(cnt_pre + 0, 256);
    if (bb < 128) {
      const int ld = bb >> 6;
      float* xr = g1pre + (size_t)bb * G4;
      const float* gg = ln_g1 + (size_t)ld * G4;
      const float* be = ln_b1 + (size_t)ld * G4;
      float v0 = aload(xr + tid), v1 = aload(xr + tid + 1024);
      float s = v0 + v1, q = v0*v0 + v1*v1;
      #pragma unroll
      for (int off = 32; off > 0; off >>= 1) { s += __shfl_down(s, off); q += __shfl_down(q, off); }
      if (l == 0) { sred[w] = s; sred[16+w] = q; }
      __syncthreads();
      float ts = 0.f, tq = 0.f;
      #pragma unroll
      for (int i = 0; i < 16; ++i) { ts += sred[i]; tq += sred[16+i]; }
      float mu = ts * (1.f/G4);
      float rstd = rsqrtf(tq*(1.f/G4) - mu*mu + EPSF);
      astore(xr + tid,        (v0-mu)*rstd*gg[tid]      + be[tid]);
      astore(xr + tid + 1024, (v1-mu)*rstd*gg[tid+1024] + be[tid+1024]);
    }
    gsync(cnt_pre + 16, 256);
  }

  // ---- role decode ----
  const int g  = bb & 7;
  const int d  = g >> 2;
  const int bq = g & 3;
  const int jb = bb >> 3;
  const int rowbase = d*BB + bq*16;
  const int ncol = jb*16 + ((l >> 4) << 9) + (l & 15);   // GEMV n-col
  int* gflags = flags + g*32;

  float wreg[32];
  {
    const float* wp = whh + ((size_t)d*G4 + ncol)*HH + (size_t)w*32;
    #pragma unroll
    for (int i = 0; i < 32; ++i) wreg[i] = wp[i];
  }

  const float* lnhg_d = lnhg + (size_t)d*G4;
  const float* lnhb_d = lnhb + (size_t)d*G4;
  const float* lnog_d = lnog + (size_t)d*HH;
  const float* lnob_d = lnob + (size_t)d*HH;
  const int rowu = rowbase + w;                 // update: wave w owns batch w
  float creg[8];
  #pragma unroll
  for (int i = 0; i < 8; ++i) { creg[i] = 0.f; hlds[w][l + 64*i] = 0.f; }
  __syncthreads();

  for (int t = 0; t < nsteps; ++t) {
    float* Rcur = Rbuf + (size_t)(t & 1) * 128 * G4;

    // ---- GEMV: wave w = k-slice [32w,32w+32), lane = n-col; uniform reads ----
    #pragma unroll
    for (int b = 0; b < 16; ++b) {
      const float* hp = &hlds[b][w*32];
      float acc = 0.f;
      #pragma unroll
      for (int i4 = 0; i4 < 8; ++i4) {
        float4 h4 = *(const float4*)(hp + 4*i4);
        acc += h4.x*wreg[4*i4+0] + h4.y*wreg[4*i4+1]
             + h4.z*wreg[4*i4+2] + h4.w*wreg[4*i4+3];
      }
      part[w][b][l] = acc;
    }
    __syncthreads();
    // ---- k-reduce + publish own R slice (thread = one (b,n) cell) ----
    {
      const int b = w, n = l;
      float r = 0.f;
      #pragma unroll
      for (int ke = 0; ke < 16; ++ke) r += part[ke][b][n];
      const int col = jb*16 + ((n >> 4) << 9) + (n & 15);
      astore(Rcur + (size_t)(rowbase + b)*G4 + col, r);
    }
    // ---- one barrier: publish flag, poll group line (no RMW) ----
    __syncthreads();   // drains vmcnt per wave before barrier => stores done
    if (tid == 0)
      __hip_atomic_store(gflags + jb, t + 1, __ATOMIC_RELEASE, AGENT);
    if (tid < 64) {
      int spins = 0;
      for (;;) {
        int v = __hip_atomic_load(gflags + (tid & 31), __ATOMIC_RELAXED, AGENT);
        #pragma unroll
        for (int off = 32; off > 0; off >>= 1) v = min(v, __shfl_down(v, off));
        v = __shfl(v, 0);
        if (v >= t + 1) break;
        __builtin_amdgcn_s_sleep(2);
        if (++spins > (1 << 20)) break;
      }
      (void)__hip_atomic_load(gflags, __ATOMIC_ACQUIRE, AGENT);
    }
    __syncthreads();

    // ---- replicated cell update: wave w = batch, lane l, cells j=l+64i ----
    {
      const float* Rrow = Rcur + (size_t)rowu * G4;
      float rv[32];
      float s = 0.f, q = 0.f;
      #pragma unroll
      for (int g4 = 0; g4 < 4; ++g4)
        #pragma unroll
        for (int i = 0; i < 8; ++i) {
          float v = aload(Rrow + g4*512 + l + 64*i);
          rv[g4*8 + i] = v; s += v; q += v*v;
        }
      #pragma unroll
      for (int off = 32; off > 0; off >>= 1) { s += __shfl_down(s, off); q += __shfl_down(q, off); }
      s = __shfl(s, 0); q = __shfl(q, 0);
      float mu = s * (1.f/G4);
      float rstd = rsqrtf(q*(1.f/G4) - mu*mu + EPSF);

      const float* gr = Gbuf + (size_t)rowu * g_row_stride + (size_t)t * g_t_stride;
      float ov[8];
      float cs = 0.f, cq = 0.f;
      #pragma unroll
      for (int i = 0; i < 8; ++i) {
        const int j = l + 64*i;
        float gi = gr[j]        + (rv[i]     - mu)*rstd*lnhg_d[j]        + lnhb_d[j];
        float gf = gr[512+j]    + (rv[8+i]   - mu)*rstd*lnhg_d[512+j]    + lnhb_d[512+j];
        float go = gr[1024+j]   + (rv[16+i]  - mu)*rstd*lnhg_d[1024+j]   + lnhb_d[1024+j];
        float gt = gr[1536+j]   + (rv[24+i]  - mu)*rstd*lnhg_d[1536+j]   + lnhb_d[1536+j];
        float iv = 1.f/(1.f+expf(-gi));
        float fv = 1.f/(1.f+expf(-gf));
        ov[i]    = 1.f/(1.f+expf(-go));
        float gv = tanhf(gt);
        creg[i] = fv*creg[i] + iv*gv;
        cs += creg[i]; cq += creg[i]*creg[i];
      }
      #pragma unroll
      for (int off = 32; off > 0; off >>= 1) { cs += __shfl_down(cs, off); cq += __shfl_down(cq, off); }
      cs = __shfl(cs, 0); cq = __shfl(cq, 0);
      float muc = cs * (1.f/HH);
      float rsc = rsqrtf(cq*(1.f/HH) - muc*muc + EPSF);
      #pragma unroll
      for (int i = 0; i < 8; ++i) {
        const int j = l + 64*i;
        hlds[w][j] = ov[i] * tanhf((creg[i] - muc)*rsc*lnog_d[j] + lnob_d[j]);
      }
    }
    __syncthreads();   // h(t) visible to all waves for next GEMV
  }

  // ---- final h -> output (one block per group writes) ----
  if (jb == 0) {
    #pragma unroll
    for (int i = 0; i < 8; ++i) {
      const int j = l + 64*i;
      fout[(size_t)(bq*16 + w) * 1024 + (size_t)d*HH + j] = hlds[w][j];
    }
  }
}

extern "C" void kernel_launch(void* const* d_in, const int* in_sizes, int n_in,
                              void* d_out, int out_size, void* d_ws, size_t ws_size,
                              hipStream_t stream) {
  const float* x        = (const float*)d_in[0];
  const float* w_ih0    = (const float*)d_in[2];
  const float* w_hh0    = (const float*)d_in[3];
  const float* ln_ih0_g = (const float*)d_in[4];
  const float* ln_ih0_b = (const float*)d_in[5];
  const float* ln_hh0_g = (const float*)d_in[6];
  const float* ln_hh0_b = (const float*)d_in[7];
  const float* ln_ho0_g = (const float*)d_in[8];
  const float* ln_ho0_b = (const float*)d_in[9];
  const float* w_ih1    = (const float*)d_in[10];
  const float* w_hh1    = (const float*)d_in[11];
  const float* ln_ih1_g = (const float*)d_in[12];
  const float* ln_ih1_b = (const float*)d_in[13];
  const float* ln_hh1_g = (const float*)d_in[14];
  const float* ln_hh1_b = (const float*)d_in[15];
  const float* ln_ho1_g = (const float*)d_in[16];
  const float* ln_ho1_b = (const float*)d_in[17];
  float* out = (float*)d_out;

  // ws (floats): G0 12.58M | g1pre 262K | xcb 64K | Rbuf 2x128x2048 (512K) |
  //              ints: flags_l0 256 | flags_l1 256 | cnt_pre 64     ~= 53.8 MB
  float* G0    = (float*)d_ws;
  float* g1pre = G0 + (size_t)2*BB*SS*G4;
  float* xcb   = g1pre + (size_t)2*BB*G4;
  float* Rbuf  = xcb + (size_t)BB*1024;
  int*   ints  = (int*)(Rbuf + (size_t)2*128*G4);
  int*   flags0  = ints;
  int*   flags1  = ints + 256;
  int*   cnt_pre = ints + 512;

  // zero all flags/counters
  hipMemsetAsync(ints, 0, 576*sizeof(int), stream);

  // phase A: G0 = LN(x @ w_ih0^T), time-reversal baked in for d=1
  hipLaunchKernelGGL(gemm_ih0, dim3(G4/64, (2*BB*SS)/64), dim3(256), 0, stream,
      x, w_ih0, G0);
  hipLaunchKernelGGL(ln_rows, dim3(2*BB*SS), dim3(256), 0, stream,
      G0, ln_ih0_g, ln_ih0_b, BB*SS);

  // layer 0 scan -> xcb
  hipLaunchKernelGGL(persist5, dim3(256), dim3(1024), 0, stream,
      w_hh0, G0, (long)SS*G4, (long)G4,
      ln_hh0_g, ln_hh0_b, ln_ho0_g, ln_ho0_b,
      Rbuf, flags0, xcb, SS,
      0, (const float*)nullptr, (const float*)nullptr, (float*)nullptr,
      (const float*)nullptr, (const float*)nullptr, (int*)nullptr);

  // layer 1: projection + LN in preamble, then scan (t-stride 0) -> out
  hipLaunchKernelGGL(persist5, dim3(256), dim3(1024), 0, stream,
      w_hh1, g1pre, (long)G4, 0L,
      ln_hh1_g, ln_hh1_b, ln_ho1_g, ln_ho1_b,
      Rbuf, flags1, out, SS,
      1, w_ih1, xcb, g1pre, ln_ih1_g, ln_ih1_b, cnt_pre);
}

// Round 9
// 4711.214 us; speedup vs baseline: 1.0196x; 1.0196x over previous
//
#include <hip/hip_runtime.h>
#include <math.h>

#define HH 512
#define BB 64
#define SS 48
#define EE 512
#define G4 2048
#define EPSF 1e-5f
#define AGENT __HIP_MEMORY_SCOPE_AGENT

__device__ __forceinline__ float aload(const float* p) {
  return __hip_atomic_load(p, __ATOMIC_RELAXED, AGENT);
}
__device__ __forceinline__ void astore(float* p, float v) {
  __hip_atomic_store(p, v, __ATOMIC_RELAXED, AGENT);
}

// counting barrier (preamble only)
__device__ __forceinline__ void gsync(int* c, int target) {
  __builtin_amdgcn_s_waitcnt(0);
  __syncthreads();
  if (threadIdx.x == 0) {
    __hip_atomic_fetch_add(c, 1, __ATOMIC_RELEASE, AGENT);
    int spins = 0;
    while (__hip_atomic_load(c, __ATOMIC_RELAXED, AGENT) < target) {
      __builtin_amdgcn_s_sleep(2);
      if (++spins > (1 << 21)) break;
    }
    (void)__hip_atomic_load(c, __ATOMIC_ACQUIRE, AGENT);
  }
  __syncthreads();
}

// ======== phase A: layer-0 input projection, full S, both dirs ========
__global__ __launch_bounds__(256)
void gemm_ih0(const float* __restrict__ x, const float* __restrict__ w_ih0,
              float* __restrict__ G0) {
  __shared__ float As[16][65];
  __shared__ float Bs[16][65];
  const int m0 = blockIdx.y * 64;
  const int d  = m0 / (BB * SS);
  const float* Wm = w_ih0 + (size_t)d * G4 * EE;
  const int bn = blockIdx.x * 64;
  const int tid = threadIdx.x;
  const int lrow = tid >> 2;
  const int lkk  = (tid & 3) << 2;
  const int tx = tid & 15;
  const int ty = tid >> 4;
  int m  = m0 + lrow;
  int r  = m - d * (BB * SS);
  int b  = r / SS;
  int tl = r - b * SS;
  int s  = d ? (SS - 1 - tl) : tl;
  const float* arow = x + ((size_t)b * SS + s) * EE;

  float acc[4][4] = {};
  for (int k0 = 0; k0 < EE; k0 += 16) {
    float4 av = *(const float4*)(arow + k0 + lkk);
    float4 bv = *(const float4*)(Wm + (size_t)(bn + lrow) * EE + k0 + lkk);
    As[lkk+0][lrow] = av.x; As[lkk+1][lrow] = av.y; As[lkk+2][lrow] = av.z; As[lkk+3][lrow] = av.w;
    Bs[lkk+0][lrow] = bv.x; Bs[lkk+1][lrow] = bv.y; Bs[lkk+2][lrow] = bv.z; Bs[lkk+3][lrow] = bv.w;
    __syncthreads();
    #pragma unroll
    for (int k = 0; k < 16; ++k) {
      float a[4], bbv[4];
      #pragma unroll
      for (int i = 0; i < 4; ++i) a[i] = As[k][ty*4+i];
      #pragma unroll
      for (int j = 0; j < 4; ++j) bbv[j] = Bs[k][tx*4+j];
      #pragma unroll
      for (int i = 0; i < 4; ++i)
        #pragma unroll
        for (int j = 0; j < 4; ++j) acc[i][j] += a[i]*bbv[j];
    }
    __syncthreads();
  }
  for (int i = 0; i < 4; ++i)
    for (int j = 0; j < 4; ++j)
      G0[(size_t)(m0 + ty*4 + i) * G4 + bn + tx*4 + j] = acc[i][j];
}

// ======== in-place LayerNorm on rows of 2048 ========
__global__ __launch_bounds__(256)
void ln_rows(float* __restrict__ X, const float* __restrict__ gamma,
             const float* __restrict__ beta, int rows_per_d) {
  __shared__ float red[8];
  const int row = blockIdx.x;
  const int d = row / rows_per_d;
  float* xr = X + (size_t)row * G4;
  const float* gg = gamma + (size_t)d * G4;
  const float* bb = beta  + (size_t)d * G4;
  float s = 0.f, q = 0.f;
  float v[8];
  #pragma unroll
  for (int it = 0; it < 8; ++it) {
    float xv = xr[threadIdx.x + it*256];
    v[it] = xv; s += xv; q += xv*xv;
  }
  #pragma unroll
  for (int off = 32; off > 0; off >>= 1) { s += __shfl_down(s, off); q += __shfl_down(q, off); }
  int lane = threadIdx.x & 63, wid = threadIdx.x >> 6;
  if (lane == 0) { red[wid] = s; red[4+wid] = q; }
  __syncthreads();
  float ts = red[0]+red[1]+red[2]+red[3];
  float tq = red[4]+red[5]+red[6]+red[7];
  float mu = ts * (1.f/G4);
  float rstd = rsqrtf(tq*(1.f/G4) - mu*mu + EPSF);
  #pragma unroll
  for (int it = 0; it < 8; ++it) {
    int jc = threadIdx.x + it*256;
    xr[jc] = (v[it]-mu)*rstd*gg[jc] + bb[jc];
  }
}

// ======== persistent scan: asymmetric owner/producer, L2-resident state ====
// group g = bb&7 = (d, bq). jb = bb>>3 in [0,32). Block jb owns 64 GEMV n-cols
// {jb*16 + q*512 + l} with weights in VGPRs. Block jb==0 is the OWNER: holds
// c in registers (wave = batch) and performs the whole cell update alone.
// Per step: owner publishes h(32KB)+hflag; producers poll hflag, stage h,
// GEMV, publish R-slice + per-block flag (no RMW); owner gather-polls 32
// flags, reads R(128KB), updates. Group state = 160KB -> L2-resident.
// Single-buffered h/R is safe: flags totally order read-before-overwrite.
__global__ __launch_bounds__(1024)
void persist6(const float* __restrict__ whh, const float* __restrict__ Gbuf,
              long g_row_stride, long g_t_stride,
              const float* __restrict__ lnhg, const float* __restrict__ lnhb,
              const float* __restrict__ lnog, const float* __restrict__ lnob,
              float* hpub, float* Rpub, int* hflag, int* rflag,
              float* fout, int nsteps,
              int mode1, const float* __restrict__ w_ih1,
              const float* __restrict__ xcb, float* g1pre,
              const float* __restrict__ ln_g1, const float* __restrict__ ln_b1,
              int* cnt_pre) {
  __shared__ float hlds[16][512];     // 32 KB
  __shared__ float part[16][16][64];  // 64 KB -> ~96 KB total => 1 block/CU
  __shared__ float sred[32];

  const int bb = blockIdx.x;
  const int tid = threadIdx.x;
  const int l = tid & 63;
  const int w = tid >> 6;

  // ---- mode1 preamble: layer-1 projection + LN(g1pre) ----
  if (mode1) {
    const int dp = bb & 1, nbp = bb >> 1;
    const int pb = tid >> 4, ns = tid & 15;
    const int col = nbp*16 + ns;
    const float* xrow = xcb + (size_t)pb * 1024;
    const float* wv_ = w_ih1 + ((size_t)dp*G4 + col) * 1024;
    float a = 0.f;
    for (int k = 0; k < 1024; k += 4) {
      float4 xv = *(const float4*)(xrow + k);
      float4 wv4 = *(const float4*)(wv_ + k);
      a += xv.x*wv4.x + xv.y*wv4.y + xv.z*wv4.z + xv.w*wv4.w;
    }
    astore(g1pre + ((size_t)dp*BB + pb) * G4 + col, a);
    gsync(cnt_pre + 0, 256);
    if (bb < 128) {
      const int ld = bb >> 6;
      float* xr = g1pre + (size_t)bb * G4;
      const float* gg = ln_g1 + (size_t)ld * G4;
      const float* be = ln_b1 + (size_t)ld * G4;
      float v0 = aload(xr + tid), v1 = aload(xr + tid + 1024);
      float s = v0 + v1, q = v0*v0 + v1*v1;
      #pragma unroll
      for (int off = 32; off > 0; off >>= 1) { s += __shfl_down(s, off); q += __shfl_down(q, off); }
      if (l == 0) { sred[w] = s; sred[16+w] = q; }
      __syncthreads();
      float ts = 0.f, tq = 0.f;
      #pragma unroll
      for (int i = 0; i < 16; ++i) { ts += sred[i]; tq += sred[16+i]; }
      float mu = ts * (1.f/G4);
      float rstd = rsqrtf(tq*(1.f/G4) - mu*mu + EPSF);
      astore(xr + tid,        (v0-mu)*rstd*gg[tid]      + be[tid]);
      astore(xr + tid + 1024, (v1-mu)*rstd*gg[tid+1024] + be[tid+1024]);
    }
    gsync(cnt_pre + 16, 256);
  }

  // ---- role decode ----
  const int g  = bb & 7;            // all blocks of a group land on one XCD
  const int d  = g >> 2;
  const int bq = g & 3;
  const int jb = bb >> 3;
  const int rowbase = d*BB + bq*16;
  const int ncol = jb*16 + ((l >> 4) << 9) + (l & 15);
  int* hf = hflag + g*32;                       // one line per group
  int* rfbase = rflag + (size_t)g*1024;         // 32 slots, 128-B stride
  float* hp_g = hpub + (size_t)g*16*HH;
  float* Rp_g = Rpub + (size_t)g*16*G4;

  float wreg[32];
  {
    const float* wp = whh + ((size_t)d*G4 + ncol)*HH + (size_t)w*32;
    #pragma unroll
    for (int i = 0; i < 32; ++i) wreg[i] = wp[i];
  }

  if (jb == 0) {
    // ================= OWNER =================
    const float* lnhg_d = lnhg + (size_t)d*G4;
    const float* lnhb_d = lnhb + (size_t)d*G4;
    const float* lnog_d = lnog + (size_t)d*HH;
    const float* lnob_d = lnob + (size_t)d*HH;
    const int rowu = rowbase + w;               // wave w owns batch w
    float creg[8];
    #pragma unroll
    for (int i = 0; i < 8; ++i) {
      creg[i] = 0.f;
      hlds[w][l + 64*i] = 0.f;
      astore(hp_g + (size_t)w*HH + l + 64*i, 0.f);   // publish h(0)=0
    }
    __builtin_amdgcn_s_waitcnt(0);
    __syncthreads();
    if (tid == 0) __hip_atomic_store(hf, 1, __ATOMIC_RELEASE, AGENT);
    __syncthreads();

    for (int t = 0; t < nsteps; ++t) {
      // ---- own GEMV slice (h already in LDS) ----
      #pragma unroll
      for (int b = 0; b < 16; ++b) {
        const float* hp = &hlds[b][w*32];
        float acc = 0.f;
        #pragma unroll
        for (int i4 = 0; i4 < 8; ++i4) {
          float4 h4 = *(const float4*)(hp + 4*i4);
          acc += h4.x*wreg[4*i4+0] + h4.y*wreg[4*i4+1]
               + h4.z*wreg[4*i4+2] + h4.w*wreg[4*i4+3];
        }
        part[w][b][l] = acc;
      }
      __syncthreads();
      {
        float r = 0.f;
        #pragma unroll
        for (int ke = 0; ke < 16; ++ke) r += part[ke][w][l];
        astore(Rp_g + (size_t)w*G4 + ncol, r);   // owner slice: jb=0 cols
      }
      __builtin_amdgcn_s_waitcnt(0);
      __syncthreads();
      if (tid == 0) __hip_atomic_store(rfbase, t + 1, __ATOMIC_RELEASE, AGENT);

      // ---- poll all 32 producer flags (one strided gather per poll) ----
      if (tid < 32) {
        int spins = 0;
        for (;;) {
          int v = __hip_atomic_load(rfbase + tid*32, __ATOMIC_RELAXED, AGENT);
          #pragma unroll
          for (int off = 16; off > 0; off >>= 1) v = min(v, __shfl_down(v, off, 32));
          v = __shfl(v, 0, 32);
          if (v >= t + 1) break;
          __builtin_amdgcn_s_sleep(1);
          if (++spins > (1 << 22)) break;
        }
        (void)__hip_atomic_load(rfbase, __ATOMIC_ACQUIRE, AGENT);
      }
      __syncthreads();

      // ---- cell update: wave w = batch, lane l, cells j = l + 64i ----
      {
        const float* Rrow = Rp_g + (size_t)w*G4;
        float rv[32];
        float s = 0.f, q = 0.f;
        #pragma unroll
        for (int g4 = 0; g4 < 4; ++g4)
          #pragma unroll
          for (int i = 0; i < 8; ++i) {
            float v = aload(Rrow + g4*512 + l + 64*i);
            rv[g4*8 + i] = v; s += v; q += v*v;
          }
        #pragma unroll
        for (int off = 32; off > 0; off >>= 1) { s += __shfl_down(s, off); q += __shfl_down(q, off); }
        s = __shfl(s, 0); q = __shfl(q, 0);
        float mu = s * (1.f/G4);
        float rstd = rsqrtf(q*(1.f/G4) - mu*mu + EPSF);

        const float* gr = Gbuf + (size_t)rowu * g_row_stride + (size_t)t * g_t_stride;
        float ov[8];
        float cs = 0.f, cq = 0.f;
        #pragma unroll
        for (int i = 0; i < 8; ++i) {
          const int j = l + 64*i;
          float gi = gr[j]        + (rv[i]    - mu)*rstd*lnhg_d[j]        + lnhb_d[j];
          float gf = gr[512+j]    + (rv[8+i]  - mu)*rstd*lnhg_d[512+j]    + lnhb_d[512+j];
          float go = gr[1024+j]   + (rv[16+i] - mu)*rstd*lnhg_d[1024+j]   + lnhb_d[1024+j];
          float gt = gr[1536+j]   + (rv[24+i] - mu)*rstd*lnhg_d[1536+j]   + lnhb_d[1536+j];
          float iv = 1.f/(1.f+expf(-gi));
          float fv = 1.f/(1.f+expf(-gf));
          ov[i]    = 1.f/(1.f+expf(-go));
          float gv = tanhf(gt);
          creg[i] = fv*creg[i] + iv*gv;
          cs += creg[i]; cq += creg[i]*creg[i];
        }
        #pragma unroll
        for (int off = 32; off > 0; off >>= 1) { cs += __shfl_down(cs, off); cq += __shfl_down(cq, off); }
        cs = __shfl(cs, 0); cq = __shfl(cq, 0);
        float muc = cs * (1.f/HH);
        float rsc = rsqrtf(cq*(1.f/HH) - muc*muc + EPSF);
        #pragma unroll
        for (int i = 0; i < 8; ++i) {
          const int j = l + 64*i;
          float hv = ov[i] * tanhf((creg[i] - muc)*rsc*lnog_d[j] + lnob_d[j]);
          hlds[w][j] = hv;
          astore(hp_g + (size_t)w*HH + j, hv);
        }
      }
      __builtin_amdgcn_s_waitcnt(0);
      __syncthreads();
      if (tid == 0) __hip_atomic_store(hf, t + 2, __ATOMIC_RELEASE, AGENT);
      __syncthreads();
    }
    // final h -> output
    #pragma unroll
    for (int i = 0; i < 8; ++i) {
      const int j = l + 64*i;
      fout[(size_t)(bq*16 + w) * 1024 + (size_t)d*HH + j] = hlds[w][j];
    }
  } else {
    // ================= PRODUCER =================
    for (int t = 0; t < nsteps; ++t) {
      if (tid == 0) {
        int spins = 0;
        while (__hip_atomic_load(hf, __ATOMIC_RELAXED, AGENT) < t + 1) {
          __builtin_amdgcn_s_sleep(1);
          if (++spins > (1 << 22)) break;
        }
        (void)__hip_atomic_load(hf, __ATOMIC_ACQUIRE, AGENT);
      }
      __syncthreads();
      // stage h (8192 floats, 8 per thread)
      #pragma unroll
      for (int i = 0; i < 8; ++i) {
        int idx = i*1024 + tid;
        hlds[idx >> 9][idx & 511] = aload(hp_g + idx);
      }
      __syncthreads();
      // GEMV: wave w = k-slice [32w, 32w+32), lane = n-col
      #pragma unroll
      for (int b = 0; b < 16; ++b) {
        const float* hp = &hlds[b][w*32];
        float acc = 0.f;
        #pragma unroll
        for (int i4 = 0; i4 < 8; ++i4) {
          float4 h4 = *(const float4*)(hp + 4*i4);
          acc += h4.x*wreg[4*i4+0] + h4.y*wreg[4*i4+1]
               + h4.z*wreg[4*i4+2] + h4.w*wreg[4*i4+3];
        }
        part[w][b][l] = acc;
      }
      __syncthreads();
      {
        float r = 0.f;
        #pragma unroll
        for (int ke = 0; ke < 16; ++ke) r += part[ke][w][l];
        astore(Rp_g + (size_t)w*G4 + ncol, r);
      }
      __builtin_amdgcn_s_waitcnt(0);
      __syncthreads();
      if (tid == 0)
        __hip_atomic_store(rfbase + jb*32, t + 1, __ATOMIC_RELEASE, AGENT);
    }
  }
}

extern "C" void kernel_launch(void* const* d_in, const int* in_sizes, int n_in,
                              void* d_out, int out_size, void* d_ws, size_t ws_size,
                              hipStream_t stream) {
  const float* x        = (const float*)d_in[0];
  const float* w_ih0    = (const float*)d_in[2];
  const float* w_hh0    = (const float*)d_in[3];
  const float* ln_ih0_g = (const float*)d_in[4];
  const float* ln_ih0_b = (const float*)d_in[5];
  const float* ln_hh0_g = (const float*)d_in[6];
  const float* ln_hh0_b = (const float*)d_in[7];
  const float* ln_ho0_g = (const float*)d_in[8];
  const float* ln_ho0_b = (const float*)d_in[9];
  const float* w_ih1    = (const float*)d_in[10];
  const float* w_hh1    = (const float*)d_in[11];
  const float* ln_ih1_g = (const float*)d_in[12];
  const float* ln_ih1_b = (const float*)d_in[13];
  const float* ln_hh1_g = (const float*)d_in[14];
  const float* ln_hh1_b = (const float*)d_in[15];
  const float* ln_ho1_g = (const float*)d_in[16];
  const float* ln_ho1_b = (const float*)d_in[17];
  float* out = (float*)d_out;

  // ws (floats): G0 12.58M | g1pre 262K | xcb 64K | hpub 64K | Rpub 256K |
  //              ints: rflag0 8192 | rflag1 8192 | hflag0 256 | hflag1 256 |
  //              cnt_pre 64                               ~= 53.0 MB + 68 KB
  float* G0    = (float*)d_ws;
  float* g1pre = G0 + (size_t)2*BB*SS*G4;
  float* xcb   = g1pre + (size_t)2*BB*G4;
  float* hpub  = xcb + (size_t)BB*1024;
  float* Rpub  = hpub + (size_t)8*16*HH;
  int*   ints  = (int*)(Rpub + (size_t)8*16*G4);
  int*   rflag0  = ints;
  int*   rflag1  = ints + 8192;
  int*   hflag0  = ints + 16384;
  int*   hflag1  = ints + 16384 + 256;
  int*   cnt_pre = ints + 16384 + 512;

  // zero all flags/counters
  hipMemsetAsync(ints, 0, (16384 + 512 + 64)*sizeof(int), stream);

  // phase A: G0 = LN(x @ w_ih0^T), time-reversal baked in for d=1
  hipLaunchKernelGGL(gemm_ih0, dim3(G4/64, (2*BB*SS)/64), dim3(256), 0, stream,
      x, w_ih0, G0);
  hipLaunchKernelGGL(ln_rows, dim3(2*BB*SS), dim3(256), 0, stream,
      G0, ln_ih0_g, ln_ih0_b, BB*SS);

  // layer 0 scan -> xcb
  hipLaunchKernelGGL(persist6, dim3(256), dim3(1024), 0, stream,
      w_hh0, G0, (long)SS*G4, (long)G4,
      ln_hh0_g, ln_hh0_b, ln_ho0_g, ln_ho0_b,
      hpub, Rpub, hflag0, rflag0, xcb, SS,
      0, (const float*)nullptr, (const float*)nullptr, (float*)nullptr,
      (const float*)nullptr, (const float*)nullptr, (int*)nullptr);

  // layer 1: projection + LN in preamble, then scan (t-stride 0) -> out
  hipLaunchKernelGGL(persist6, dim3(256), dim3(1024), 0, stream,
      w_hh1, g1pre, (long)G4, 0L,
      ln_hh1_g, ln_hh1_b, ln_ho1_g, ln_ho1_b,
      hpub, Rpub, hflag1, rflag1, out, SS,
      1, w_ih1, xcb, g1pre, ln_ih1_g, ln_ih1_b, cnt_pre);
}

// Round 10
// 1847.432 us; speedup vs baseline: 2.6002x; 2.5501x over previous
//
#include <hip/hip_runtime.h>
#include <math.h>

#define HH 512
#define BB 64
#define SS 48
#define EE 512
#define G4 2048
#define EPSF 1e-5f
#define AGENT __HIP_MEMORY_SCOPE_AGENT

__device__ __forceinline__ float aload(const float* p) {
  return __hip_atomic_load(p, __ATOMIC_RELAXED, AGENT);   // sc1: MALL-coherent
}
__device__ __forceinline__ void astore(float* p, float v) {
  __hip_atomic_store(p, v, __ATOMIC_RELAXED, AGENT);
}

// counting barrier (preamble only; acquire OK here, runs twice per call)
__device__ __forceinline__ void gsync(int* c, int target) {
  __builtin_amdgcn_s_waitcnt(0);
  __syncthreads();
  if (threadIdx.x == 0) {
    __hip_atomic_fetch_add(c, 1, __ATOMIC_RELEASE, AGENT);
    int spins = 0;
    while (__hip_atomic_load(c, __ATOMIC_RELAXED, AGENT) < target) {
      __builtin_amdgcn_s_sleep(2);
      if (++spins > (1 << 21)) break;
    }
    (void)__hip_atomic_load(c, __ATOMIC_ACQUIRE, AGENT);
  }
  __syncthreads();
}

// ======== phase A: layer-0 input projection, full S, both dirs ========
__global__ __launch_bounds__(256)
void gemm_ih0(const float* __restrict__ x, const float* __restrict__ w_ih0,
              float* __restrict__ G0) {
  __shared__ float As[16][65];
  __shared__ float Bs[16][65];
  const int m0 = blockIdx.y * 64;
  const int d  = m0 / (BB * SS);
  const float* Wm = w_ih0 + (size_t)d * G4 * EE;
  const int bn = blockIdx.x * 64;
  const int tid = threadIdx.x;
  const int lrow = tid >> 2;
  const int lkk  = (tid & 3) << 2;
  const int tx = tid & 15;
  const int ty = tid >> 4;
  int m  = m0 + lrow;
  int r  = m - d * (BB * SS);
  int b  = r / SS;
  int tl = r - b * SS;
  int s  = d ? (SS - 1 - tl) : tl;
  const float* arow = x + ((size_t)b * SS + s) * EE;

  float acc[4][4] = {};
  for (int k0 = 0; k0 < EE; k0 += 16) {
    float4 av = *(const float4*)(arow + k0 + lkk);
    float4 bv = *(const float4*)(Wm + (size_t)(bn + lrow) * EE + k0 + lkk);
    As[lkk+0][lrow] = av.x; As[lkk+1][lrow] = av.y; As[lkk+2][lrow] = av.z; As[lkk+3][lrow] = av.w;
    Bs[lkk+0][lrow] = bv.x; Bs[lkk+1][lrow] = bv.y; Bs[lkk+2][lrow] = bv.z; Bs[lkk+3][lrow] = bv.w;
    __syncthreads();
    #pragma unroll
    for (int k = 0; k < 16; ++k) {
      float a[4], bbv[4];
      #pragma unroll
      for (int i = 0; i < 4; ++i) a[i] = As[k][ty*4+i];
      #pragma unroll
      for (int j = 0; j < 4; ++j) bbv[j] = Bs[k][tx*4+j];
      #pragma unroll
      for (int i = 0; i < 4; ++i)
        #pragma unroll
        for (int j = 0; j < 4; ++j) acc[i][j] += a[i]*bbv[j];
    }
    __syncthreads();
  }
  for (int i = 0; i < 4; ++i)
    for (int j = 0; j < 4; ++j)
      G0[(size_t)(m0 + ty*4 + i) * G4 + bn + tx*4 + j] = acc[i][j];
}

// ======== in-place LayerNorm on rows of 2048 ========
__global__ __launch_bounds__(256)
void ln_rows(float* __restrict__ X, const float* __restrict__ gamma,
             const float* __restrict__ beta, int rows_per_d) {
  __shared__ float red[8];
  const int row = blockIdx.x;
  const int d = row / rows_per_d;
  float* xr = X + (size_t)row * G4;
  const float* gg = gamma + (size_t)d * G4;
  const float* bb = beta  + (size_t)d * G4;
  float s = 0.f, q = 0.f;
  float v[8];
  #pragma unroll
  for (int it = 0; it < 8; ++it) {
    float xv = xr[threadIdx.x + it*256];
    v[it] = xv; s += xv; q += xv*xv;
  }
  #pragma unroll
  for (int off = 32; off > 0; off >>= 1) { s += __shfl_down(s, off); q += __shfl_down(q, off); }
  int lane = threadIdx.x & 63, wid = threadIdx.x >> 6;
  if (lane == 0) { red[wid] = s; red[4+wid] = q; }
  __syncthreads();
  float ts = red[0]+red[1]+red[2]+red[3];
  float tq = red[4]+red[5]+red[6]+red[7];
  float mu = ts * (1.f/G4);
  float rstd = rsqrtf(tq*(1.f/G4) - mu*mu + EPSF);
  #pragma unroll
  for (int it = 0; it < 8; ++it) {
    int jc = threadIdx.x + it*256;
    xr[jc] = (v[it]-mu)*rstd*gg[jc] + bb[jc];
  }
}

// ======== persistent scan: R7 structure, fence-free flag barriers ========
// group g = bb&7 = (d, bq); jb = bb>>3 in [0,32). Block owns 64 n-cols
// {jb*16 + q*512 + l} (co-located gates for j-slice jb*16..+16), batches
// bq*16..+16. All cross-block data moves via sc1 (MALL-coherent) relaxed
// atomics; flags are per-block monotone counters at 128-B stride (no RMW,
// no acquire, no L2 invalidate anywhere in the step loop).
__global__ __launch_bounds__(1024, 4)
void persist7(const float* __restrict__ whh, const float* __restrict__ Gbuf,
              long g_row_stride, long g_t_stride,
              const float* __restrict__ lnhg, const float* __restrict__ lnhb,
              const float* __restrict__ lnog, const float* __restrict__ lnob,
              float* cbuf, float* obuf, float* Rpart, float* Cpart,
              int* flagsA, int* flagsB,
              float* fout, int nsteps,
              int mode1, const float* __restrict__ w_ih1,
              const float* __restrict__ xcb, float* g1pre,
              const float* __restrict__ ln_g1, const float* __restrict__ ln_b1,
              int* cnt_pre) {
  __shared__ float hlds[16][1024];    // 64 KB (cols 0..511 used; pads LDS)
  __shared__ float part[16][8][64];   // 32 KB
  __shared__ float redR[16][64];      //  4 KB
  __shared__ float bcR[16][2];
  __shared__ float bcC[16][2];
  __shared__ float sred[32];

  const int bb = blockIdx.x;
  const int tid = threadIdx.x;

  // ---- mode1 preamble: layer-1 projection + LN(g1pre) ----
  if (mode1) {
    const int dp = bb & 1, nbp = bb >> 1;
    const int pb = tid >> 4, ns = tid & 15;
    const int col = nbp*16 + ns;
    const float* xrow = xcb + (size_t)pb * 1024;
    const float* wv_ = w_ih1 + ((size_t)dp*G4 + col) * 1024;
    float a = 0.f;
    for (int k = 0; k < 1024; k += 4) {
      float4 xv = *(const float4*)(xrow + k);
      float4 wv4 = *(const float4*)(wv_ + k);
      a += xv.x*wv4.x + xv.y*wv4.y + xv.z*wv4.z + xv.w*wv4.w;
    }
    astore(g1pre + ((size_t)dp*BB + pb) * G4 + col, a);
    gsync(cnt_pre + 0, 256);
    if (bb < 128) {
      const int ld = bb >> 6;
      float* xr = g1pre + (size_t)bb * G4;
      const float* gg = ln_g1 + (size_t)ld * G4;
      const float* be = ln_b1 + (size_t)ld * G4;
      float v0 = aload(xr + tid), v1 = aload(xr + tid + 1024);
      float s = v0 + v1, q = v0*v0 + v1*v1;
      #pragma unroll
      for (int off = 32; off > 0; off >>= 1) { s += __shfl_down(s, off); q += __shfl_down(q, off); }
      const int wv2 = tid >> 6;
      if ((tid & 63) == 0) { sred[wv2] = s; sred[16+wv2] = q; }
      __syncthreads();
      float ts = 0.f, tq = 0.f;
      #pragma unroll
      for (int i = 0; i < 16; ++i) { ts += sred[i]; tq += sred[16+i]; }
      float mu = ts * (1.f/G4);
      float rstd = rsqrtf(tq*(1.f/G4) - mu*mu + EPSF);
      astore(xr + tid,        (v0-mu)*rstd*gg[tid]      + be[tid]);
      astore(xr + tid + 1024, (v1-mu)*rstd*gg[tid+1024] + be[tid+1024]);
    }
    gsync(cnt_pre + 16, 256);
  }

  // ---- role decode ----
  const int g  = bb & 7;
  const int d  = g >> 2;
  const int bq = g & 3;
  const int jb = bb >> 3;
  const int rowbase = d*BB + bq*16;
  const int ke = tid >> 6, nl = tid & 63;       // GEMV: wave=k-slice, lane=col
  const int ncol = jb*16 + ((nl>>4) << 9) + (nl & 15);
  int* fA = flagsA + g*1024;                    // 32 slots x 32-int stride
  int* fB = flagsB + g*1024;

  float wreg[32];
  {
    const float* wp = whh + ((size_t)d*G4 + ncol)*HH + (size_t)ke*32;
    #pragma unroll
    for (int i = 0; i < 32; ++i) wreg[i] = wp[i];
  }

  const int bl = tid >> 4, jl = tid & 15;       // update role (tid<256)
  const int rowc = rowbase + bl;
  const int jc = jb*16 + jl;
  const int scol = tid & 511, srh = tid >> 9;   // staging col, row-half
  const float ogv = lnog[(size_t)d*HH + scol];
  const float obv = lnob[(size_t)d*HH + scol];
  const int row16 = tid >> 5, j32 = tid & 31;   // reduce roles (tid<512)
  const int inv_g = (g_t_stride == 0);

  // ---- hoist step-invariant update params into registers ----
  float hg0=0,hg1=0,hg2=0,hg3=0, hb0=0,hb1=0,hb2=0,hb3=0;
  float cg0=0,cg1=0,cg2=0,cg3=0;                // constant G (layer 1)
  if (tid < 256) {
    const float* lnhg_d = lnhg + (size_t)d*G4;
    const float* lnhb_d = lnhb + (size_t)d*G4;
    hg0 = lnhg_d[jc];        hb0 = lnhb_d[jc];
    hg1 = lnhg_d[HH+jc];     hb1 = lnhb_d[HH+jc];
    hg2 = lnhg_d[2*HH+jc];   hb2 = lnhb_d[2*HH+jc];
    hg3 = lnhg_d[3*HH+jc];   hb3 = lnhb_d[3*HH+jc];
    if (inv_g) {
      const float* gr = Gbuf + (size_t)rowc * g_row_stride;
      cg0 = gr[jc]; cg1 = gr[HH+jc]; cg2 = gr[2*HH+jc]; cg3 = gr[3*HH+jc];
    }
  }
  float creg = 0.f;

  for (int t = 0; t < nsteps; ++t) {
    // ---- staging: h(t-1) = o * tanh(LN(c)); 8 rows x 512 per half ----
    float cv[8], ovv[8];
    #pragma unroll
    for (int i = 0; i < 8; ++i) {
      int row = i*2 + srh;
      cv[i]  = aload(cbuf + (size_t)(rowbase + row)*512 + scol);
      ovv[i] = aload(obuf + (size_t)(rowbase + row)*512 + scol);
    }
    if (tid < 512) {
      float s = aload(Cpart + ((size_t)(rowbase+row16)*32 + j32)*2 + 0);
      float q = aload(Cpart + ((size_t)(rowbase+row16)*32 + j32)*2 + 1);
      #pragma unroll
      for (int off = 16; off > 0; off >>= 1) { s += __shfl_down(s, off, 32); q += __shfl_down(q, off, 32); }
      if (j32 == 0) {
        float mu = s * (1.f/HH);
        bcC[row16][0] = mu;
        bcC[row16][1] = rsqrtf(q*(1.f/HH) - mu*mu + EPSF);
      }
    }
    __syncthreads();
    #pragma unroll
    for (int i = 0; i < 8; ++i) {
      int row = i*2 + srh;
      hlds[row][scol] = ovv[i] * tanhf((cv[i] - bcC[row][0]) * bcC[row][1] * ogv + obv);
    }
    __syncthreads();

    // ---- GEMV in two b-halves ----
    #pragma unroll
    for (int half = 0; half < 2; ++half) {
      #pragma unroll
      for (int b = 0; b < 8; ++b) {
        const float* hp = &hlds[half*8 + b][ke*32];
        float acc = 0.f;
        #pragma unroll
        for (int i4 = 0; i4 < 8; ++i4) {
          float4 h4 = *(const float4*)(hp + 4*i4);
          acc += h4.x*wreg[4*i4+0] + h4.y*wreg[4*i4+1]
               + h4.z*wreg[4*i4+2] + h4.w*wreg[4*i4+3];
        }
        part[ke][b][nl] = acc;
      }
      __syncthreads();
      if (tid < 512) {
        int b = tid >> 6, n2 = tid & 63;
        float r = 0.f;
        #pragma unroll
        for (int k16 = 0; k16 < 16; ++k16) r += part[k16][b][n2];
        redR[half*8 + b][n2] = r;
      }
      __syncthreads();
    }
    // ---- R LN partials for this block's 64 cols ----
    if (tid < 512) {
      float v1 = redR[row16][j32], v2 = redR[row16][j32+32];
      float s = v1 + v2, q = v1*v1 + v2*v2;
      #pragma unroll
      for (int off = 16; off > 0; off >>= 1) { s += __shfl_down(s, off, 32); q += __shfl_down(q, off, 32); }
      if (j32 == 0) {
        astore(Rpart + ((size_t)(rowbase+row16)*32 + jb)*2 + 0, s);
        astore(Rpart + ((size_t)(rowbase+row16)*32 + jb)*2 + 1, q);
      }
    }
    // ---- prefetch gate row for this t (plain cached; L2 stays warm) ----
    float pg0 = cg0, pg1 = cg1, pg2 = cg2, pg3 = cg3;
    if (tid < 256 && !inv_g) {
      const float* gr = Gbuf + (size_t)rowc * g_row_stride + (size_t)t * g_t_stride;
      pg0 = gr[jc]; pg1 = gr[HH+jc]; pg2 = gr[2*HH+jc]; pg3 = gr[3*HH+jc];
    }
    // ---- barrier A: flag publish + gather-min detect (no RMW, no fence) ----
    __syncthreads();   // drains vmcnt => Rpart stores are at MALL
    if (tid == 0) __hip_atomic_store(fA + jb*32, t + 1, __ATOMIC_RELAXED, AGENT);
    if (tid < 32) {
      int spins = 0;
      for (;;) {
        int v = __hip_atomic_load(fA + tid*32, __ATOMIC_RELAXED, AGENT);
        #pragma unroll
        for (int off = 16; off > 0; off >>= 1) v = min(v, __shfl_down(v, off, 32));
        v = __shfl(v, 0, 32);
        if (v >= t + 1) break;
        __builtin_amdgcn_s_sleep(1);
        if (++spins > (1 << 22)) break;
      }
    }
    __syncthreads();

    // ---- reduce Rpart -> (mu, rstd) per row ----
    if (tid < 512) {
      float s = aload(Rpart + ((size_t)(rowbase+row16)*32 + j32)*2 + 0);
      float q = aload(Rpart + ((size_t)(rowbase+row16)*32 + j32)*2 + 1);
      #pragma unroll
      for (int off = 16; off > 0; off >>= 1) { s += __shfl_down(s, off, 32); q += __shfl_down(q, off, 32); }
      if (j32 == 0) {
        float mu = s * (1.f/G4);
        bcR[row16][0] = mu;
        bcR[row16][1] = rsqrtf(q*(1.f/G4) - mu*mu + EPSF);
      }
    }
    __syncthreads();

    // ---- gates + cell update + publish (tid<256: 16b x 16j tile) ----
    if (tid < 256) {
      float mu = bcR[bl][0], rstd = bcR[bl][1];
      float gi = pg0 + (redR[bl][jl]    - mu)*rstd*hg0 + hb0;
      float gf = pg1 + (redR[bl][16+jl] - mu)*rstd*hg1 + hb1;
      float go = pg2 + (redR[bl][32+jl] - mu)*rstd*hg2 + hb2;
      float gt = pg3 + (redR[bl][48+jl] - mu)*rstd*hg3 + hb3;
      float iv = 1.f/(1.f+expf(-gi)), fv = 1.f/(1.f+expf(-gf));
      float ov = 1.f/(1.f+expf(-go)), gv = tanhf(gt);
      creg = fv*creg + iv*gv;
      float cs = creg, cq = creg*creg;
      #pragma unroll
      for (int off = 8; off > 0; off >>= 1) { cs += __shfl_down(cs, off, 16); cq += __shfl_down(cq, off, 16); }
      if (jl == 0) {
        astore(Cpart + ((size_t)rowc*32 + jb)*2 + 0, cs);
        astore(Cpart + ((size_t)rowc*32 + jb)*2 + 1, cq);
      }
      astore(cbuf + (size_t)rowc*512 + jc, creg);
      astore(obuf + (size_t)rowc*512 + jc, ov);
    }
    // ---- barrier B ----
    __syncthreads();   // drains vmcnt => c/o/Cpart stores at MALL
    if (tid == 0) __hip_atomic_store(fB + jb*32, t + 1, __ATOMIC_RELAXED, AGENT);
    if (tid < 32) {
      int spins = 0;
      for (;;) {
        int v = __hip_atomic_load(fB + tid*32, __ATOMIC_RELAXED, AGENT);
        #pragma unroll
        for (int off = 16; off > 0; off >>= 1) v = min(v, __shfl_down(v, off, 32));
        v = __shfl(v, 0, 32);
        if (v >= t + 1) break;
        __builtin_amdgcn_s_sleep(1);
        if (++spins > (1 << 22)) break;
      }
    }
    __syncthreads();
  }

  // ---- final h -> output (jb==0 block of each group writes its 16 rows) ----
  {
    float cv[8], ovv[8];
    #pragma unroll
    for (int i = 0; i < 8; ++i) {
      int row = i*2 + srh;
      cv[i]  = aload(cbuf + (size_t)(rowbase + row)*512 + scol);
      ovv[i] = aload(obuf + (size_t)(rowbase + row)*512 + scol);
    }
    if (tid < 512) {
      float s = aload(Cpart + ((size_t)(rowbase+row16)*32 + j32)*2 + 0);
      float q = aload(Cpart + ((size_t)(rowbase+row16)*32 + j32)*2 + 1);
      #pragma unroll
      for (int off = 16; off > 0; off >>= 1) { s += __shfl_down(s, off, 32); q += __shfl_down(q, off, 32); }
      if (j32 == 0) {
        float mu = s * (1.f/HH);
        bcC[row16][0] = mu;
        bcC[row16][1] = rsqrtf(q*(1.f/HH) - mu*mu + EPSF);
      }
    }
    __syncthreads();
    if (jb == 0) {
      #pragma unroll
      for (int i = 0; i < 8; ++i) {
        int row = i*2 + srh;
        float h = ovv[i] * tanhf((cv[i] - bcC[row][0]) * bcC[row][1] * ogv + obv);
        fout[(size_t)(bq*16 + row) * 1024 + (size_t)d*512 + scol] = h;
      }
    }
  }
}

extern "C" void kernel_launch(void* const* d_in, const int* in_sizes, int n_in,
                              void* d_out, int out_size, void* d_ws, size_t ws_size,
                              hipStream_t stream) {
  const float* x        = (const float*)d_in[0];
  const float* w_ih0    = (const float*)d_in[2];
  const float* w_hh0    = (const float*)d_in[3];
  const float* ln_ih0_g = (const float*)d_in[4];
  const float* ln_ih0_b = (const float*)d_in[5];
  const float* ln_hh0_g = (const float*)d_in[6];
  const float* ln_hh0_b = (const float*)d_in[7];
  const float* ln_ho0_g = (const float*)d_in[8];
  const float* ln_ho0_b = (const float*)d_in[9];
  const float* w_ih1    = (const float*)d_in[10];
  const float* w_hh1    = (const float*)d_in[11];
  const float* ln_ih1_g = (const float*)d_in[12];
  const float* ln_ih1_b = (const float*)d_in[13];
  const float* ln_hh1_g = (const float*)d_in[14];
  const float* ln_hh1_b = (const float*)d_in[15];
  const float* ln_ho1_g = (const float*)d_in[16];
  const float* ln_ho1_b = (const float*)d_in[17];
  float* out = (float*)d_out;

  // ws (floats): G0 12.58M | g1pre 262K | xcb 64K | Rpart 8K |
  //   [zero region: Cpart 8K | cbuf 64K | obuf 64K | flags 32832 ints] ~= 52.4 MB
  float* G0    = (float*)d_ws;
  float* g1pre = G0 + (size_t)2*BB*SS*G4;
  float* xcb   = g1pre + (size_t)2*BB*G4;
  float* Rpart = xcb + (size_t)BB*1024;
  float* Cpart = Rpart + (size_t)128*32*2;
  float* cbuf  = Cpart + (size_t)128*32*2;
  float* obuf  = cbuf + (size_t)128*512;
  int*   ints  = (int*)(obuf + (size_t)128*512);
  int*   fA0     = ints;                 // 8*1024
  int*   fB0     = ints + 8192;
  int*   fA1     = ints + 16384;
  int*   fB1     = ints + 24576;
  int*   cnt_pre = ints + 32768;         // 64 ints

  // zero Cpart + cbuf + obuf + all flags/counters (contiguous)
  hipMemsetAsync(Cpart, 0, ((size_t)128*32*2 + 2*(size_t)128*512)*sizeof(float)
                           + 32832*sizeof(int), stream);

  // phase A: G0 = LN(x @ w_ih0^T), time-reversal baked in for d=1
  hipLaunchKernelGGL(gemm_ih0, dim3(G4/64, (2*BB*SS)/64), dim3(256), 0, stream,
      x, w_ih0, G0);
  hipLaunchKernelGGL(ln_rows, dim3(2*BB*SS), dim3(256), 0, stream,
      G0, ln_ih0_g, ln_ih0_b, BB*SS);

  // layer 0 scan -> xcb
  hipLaunchKernelGGL(persist7, dim3(256), dim3(1024), 0, stream,
      w_hh0, G0, (long)SS*G4, (long)G4,
      ln_hh0_g, ln_hh0_b, ln_ho0_g, ln_ho0_b,
      cbuf, obuf, Rpart, Cpart, fA0, fB0, xcb, SS,
      0, (const float*)nullptr, (const float*)nullptr, (float*)nullptr,
      (const float*)nullptr, (const float*)nullptr, (int*)nullptr);

  // re-zero Cpart + cbuf + obuf for layer 1 (flags: layer 1 has own regions)
  hipMemsetAsync(Cpart, 0, ((size_t)128*32*2 + 2*(size_t)128*512)*sizeof(float), stream);

  // layer 1: projection + LN in preamble, then scan (t-stride 0) -> out
  hipLaunchKernelGGL(persist7, dim3(256), dim3(1024), 0, stream,
      w_hh1, g1pre, (long)G4, 0L,
      ln_hh1_g, ln_hh1_b, ln_ho1_g, ln_ho1_b,
      cbuf, obuf, Rpart, Cpart, fA1, fB1, out, SS,
      1, w_ih1, xcb, g1pre, ln_ih1_g, ln_ih1_b, cnt_pre);
}